// Round 1
// baseline (571.541 us; speedup 1.0000x reference)
//
#include <hip/hip_runtime.h>
#include <math.h>

// Problem constants
#define BSZ 64
#define NPTS 512
#define DIM 256
#define MROWS 32768      // BSZ*NPTS
#define TOTROWS 65536
#define BIGF 1.0e9f

typedef __bf16 bf16x8 __attribute__((ext_vector_type(8)));
typedef float  f32x4  __attribute__((ext_vector_type(4)));

// ws layout (float offsets)
#define KB_OFF    0ull          // 8388608 floats as ushort[16777216]: Ybf1 -> Ybf2 -> K(bf16)
#define X_OFF     8388608ull    // 8388608 floats as ushort[16777216]: Xbf -> Ebf
#define H_OFF     16777216ull   // 8388608 floats as ushort[16777216]: Hbf ; dead after gemm2 -> gcp
#define NORM_OFF  25165824ull   // 65536 f32
#define U_OFF     25231360ull   // 32768 f32
#define V_OFF     25264128ull   // 32768 f32
#define ARGA_OFF  25296896ull   // 32768 int
#define ARGB_OFF  25329664ull   // 32768 int
#define ACC_OFF   25362432ull   // 512 f32 (321 acc + barrier counters at +384)
#define WT1_OFF   25362944ull   // 32768 floats as ushort[65536]
#define WT2_OFF   25395712ull   // 32768 floats as ushort[65536]

#define ACC_PA   0
#define ACC_IN   1     // 64 slots
#define ACC_SUP  65    // 256 slots
#define ACC_CNT  321
#define BAR_IDX  384   // 64 uint barrier counters (within the 512-float ACC block)

__device__ __forceinline__ float bf2f(unsigned short h) {
    return __uint_as_float(((unsigned int)h) << 16);
}
__device__ __forceinline__ unsigned short f2bf(float f) {
    unsigned int u = __float_as_uint(f);
    u = (u + 0x7FFFu + ((u >> 16) & 1u)) >> 16;
    return (unsigned short)u;
}

// re-entrant
__device__ __forceinline__ float block_reduce_256(float val) {
    __shared__ float sh[4];
    int lane = threadIdx.x & 63;
    int wv = threadIdx.x >> 6;
    __syncthreads();
#pragma unroll
    for (int off = 32; off > 0; off >>= 1) val += __shfl_down(val, off, 64);
    if (lane == 0) sh[wv] = val;
    __syncthreads();
    float r = 0.f;
    if (wv == 0 && lane < 4) r = sh[lane];
    if (wv == 0) {
        r += __shfl_down(r, 2, 64);
        r += __shfl_down(r, 1, 64);
    }
    return r;  // valid in thread 0
}

__global__ void zero_acc_kernel(float* acc) {
    int t = blockIdx.x * 256 + threadIdx.x;
    if (t < 512) acc[t] = 0.f;   // zeroes ACC slots AND barrier counters at +384
}

__global__ __launch_bounds__(256) void argmax_pa_kernel(
    const float* __restrict__ la, const float* __restrict__ lb,
    const float* __restrict__ pa, int* __restrict__ argA, int* __restrict__ argB,
    float* __restrict__ acc) {
    int i = blockIdx.x * 256 + threadIdx.x;
    float4 a = *(const float4*)&la[(size_t)i * 4];
    float av[4] = {a.x, a.y, a.z, a.w};
    int ba = 0; float bv = av[0];
#pragma unroll
    for (int c = 1; c < 4; ++c) if (av[c] > bv) { bv = av[c]; ba = c; }
    argA[i] = ba;
    float4 b = *(const float4*)&lb[(size_t)i * 4];
    float bw[4] = {b.x, b.y, b.z, b.w};
    int bbi = 0; float bm = bw[0];
#pragma unroll
    for (int c = 1; c < 4; ++c) if (bw[c] > bm) { bm = bw[c]; bbi = c; }
    argB[i] = bbi;
    float p = pa[i];
#pragma unroll
    for (int off = 32; off > 0; off >>= 1) p += __shfl_down(p, off, 64);
    if ((threadIdx.x & 63) == 0) atomicAdd(&acc[ACC_PA], p);
}

// f32 -> bf16 bulk cast; grid 2048x256, 4 float4-groups/thread
__global__ __launch_bounds__(256) void cast_bf_kernel(
    const float* __restrict__ src, unsigned short* __restrict__ dst) {
    int tid = blockIdx.x * 256 + threadIdx.x;      // < 524288
#pragma unroll
    for (int k = 0; k < 4; ++k) {
        int i4 = tid + k * 524288;                 // < 2097152
        float4 v = *(const float4*)&src[(size_t)i4 * 4];
        ushort4 o;
        o.x = f2bf(v.x); o.y = f2bf(v.y); o.z = f2bf(v.z); o.w = f2bf(v.w);
        *(ushort4*)&dst[(size_t)i4 * 4] = o;
    }
}

// W[256][256] f32 -> Wt[n][k] bf16 (transposed)
__global__ __launch_bounds__(256) void cast_wt_kernel(
    const float* __restrict__ W, unsigned short* __restrict__ Wt) {
    __shared__ float tile[16][17];
    int tx = threadIdx.x & 15, ty = threadIdx.x >> 4;
    int bx = blockIdx.x, by = blockIdx.y;
    tile[ty][tx] = W[(size_t)(by * 16 + ty) * 256 + bx * 16 + tx];
    __syncthreads();
    Wt[(size_t)(bx * 16 + ty) * 256 + by * 16 + tx] = f2bf(tile[tx][ty]);
}

// Y(bf16) = X(bf16, Mx256) @ W via Wt (bf16, transposed [n][k])
__global__ __launch_bounds__(256) void gemm_bf_kernel(
    const unsigned short* __restrict__ X, const unsigned short* __restrict__ Wt,
    unsigned short* __restrict__ Y) {
    __shared__ unsigned short Xs[64 * 40];
    __shared__ unsigned short Ws[256 * 40];
    const int t = threadIdx.x;
    const int L = t & 63, wv = t >> 6;
    const int q = L >> 4, n = L & 15;
    const size_t row0 = (size_t)blockIdx.x * 64;
    f32x4 acc[16];
#pragma unroll
    for (int nt = 0; nt < 16; ++nt) acc[nt] = (f32x4){0.f, 0.f, 0.f, 0.f};

    for (int k0 = 0; k0 < 256; k0 += 32) {
        {
            int r = t >> 2, seg = t & 3;
            *(uint4*)&Xs[r * 40 + seg * 8] =
                *(const uint4*)&X[(row0 + r) * 256 + k0 + seg * 8];
#pragma unroll
            for (int it = 0; it < 4; ++it) {
                int nn = (t >> 2) + it * 64;
                *(uint4*)&Ws[nn * 40 + seg * 8] =
                    *(const uint4*)&Wt[(size_t)nn * 256 + k0 + seg * 8];
            }
        }
        __syncthreads();
        bf16x8 av = *(const bf16x8*)&Xs[(wv * 16 + n) * 40 + q * 8];
#pragma unroll
        for (int nt = 0; nt < 16; ++nt) {
            bf16x8 bv = *(const bf16x8*)&Ws[(nt * 16 + n) * 40 + q * 8];
            acc[nt] = __builtin_amdgcn_mfma_f32_16x16x32_bf16(av, bv, acc[nt], 0, 0, 0);
        }
        __syncthreads();
    }
#pragma unroll
    for (int nt = 0; nt < 16; ++nt)
#pragma unroll
        for (int r = 0; r < 4; ++r) {
            size_t row = row0 + wv * 16 + q * 4 + r;
            Y[row * 256 + nt * 16 + n] = f2bf(acc[nt][r]);
        }
}

// y_bf16_out = LN(leaky_relu(y_bf16_in + bias)) * g + be ; optional row sq-norms
__global__ __launch_bounds__(256) void ln_bf_kernel(
    const unsigned short* __restrict__ Yin, unsigned short* __restrict__ Yout,
    const float* __restrict__ bias, const float* __restrict__ gam,
    const float* __restrict__ bet, float* __restrict__ norms) {
    int lane = threadIdx.x & 63;
    int wv = threadIdx.x >> 6;
    size_t row = (size_t)blockIdx.x * 4 + wv;
    ushort4 y4 = *(const ushort4*)&Yin[row * 256 + lane * 4];
    float4 b4 = *(const float4*)&bias[lane * 4];
    float h[4] = {bf2f(y4.x) + b4.x, bf2f(y4.y) + b4.y, bf2f(y4.z) + b4.z, bf2f(y4.w) + b4.w};
#pragma unroll
    for (int e = 0; e < 4; ++e) h[e] = h[e] >= 0.f ? h[e] : 0.01f * h[e];
    float s = h[0] + h[1] + h[2] + h[3];
    float sq = h[0] * h[0] + h[1] * h[1] + h[2] * h[2] + h[3] * h[3];
#pragma unroll
    for (int off = 32; off > 0; off >>= 1) {
        s += __shfl_down(s, off, 64);
        sq += __shfl_down(sq, off, 64);
    }
    s = __shfl(s, 0, 64); sq = __shfl(sq, 0, 64);
    float mean = s * (1.f / 256.f);
    float var = fmaxf(sq * (1.f / 256.f) - mean * mean, 0.f);
    float inv = rsqrtf(var + 1e-5f);
    float4 g4 = *(const float4*)&gam[lane * 4];
    float4 e4 = *(const float4*)&bet[lane * 4];
    float gv[4] = {g4.x, g4.y, g4.z, g4.w};
    float ev[4] = {e4.x, e4.y, e4.z, e4.w};
    ushort4 o4; float nr = 0.f;
    {
        unsigned short ob[4];
#pragma unroll
        for (int e = 0; e < 4; ++e) {
            float o = (h[e] - mean) * inv * gv[e] + ev[e];
            ob[e] = f2bf(o);
            float orr = bf2f(ob[e]);
            nr += orr * orr;
        }
        o4.x = ob[0]; o4.y = ob[1]; o4.z = ob[2]; o4.w = ob[3];
    }
    *(ushort4*)&Yout[row * 256 + lane * 4] = o4;
    if (norms) {
#pragma unroll
        for (int off = 32; off > 0; off >>= 1) nr += __shfl_down(nr, off, 64);
        if (lane == 0) norms[row] = nr;
    }
}

// cdist via MFMA + in/out loss partial + K(bf16) = exp(-2*cost)
__global__ __launch_bounds__(256) void cost_mfma_kernel(
    const unsigned short* __restrict__ E, const float* __restrict__ norms,
    const int* __restrict__ argA, const int* __restrict__ argB,
    const float* __restrict__ pa, const float* __restrict__ pb,
    unsigned short* __restrict__ Kb16, float* __restrict__ acc) {
    __shared__ unsigned short As[64 * 40];
    __shared__ unsigned short Bs[64 * 40];
    const int t = threadIdx.x;
    const int L = t & 63, wv = t >> 6;
    const int q = L >> 4, n = L & 15;
    const int b = blockIdx.z;
    const int i0 = blockIdx.y * 64, j0 = blockIdx.x * 64;
    const unsigned short* eA = E + (size_t)b * 512 * 256;
    const unsigned short* eB = E + (size_t)(32768 + b * 512) * 256;
    f32x4 dot[4];
#pragma unroll
    for (int nt = 0; nt < 4; ++nt) dot[nt] = (f32x4){0.f, 0.f, 0.f, 0.f};

    for (int k0 = 0; k0 < 256; k0 += 32) {
        int r = t >> 2, seg = t & 3;
        *(uint4*)&As[r * 40 + seg * 8] =
            *(const uint4*)&eA[(size_t)(i0 + r) * 256 + k0 + seg * 8];
        *(uint4*)&Bs[r * 40 + seg * 8] =
            *(const uint4*)&eB[(size_t)(j0 + r) * 256 + k0 + seg * 8];
        __syncthreads();
        bf16x8 av = *(const bf16x8*)&As[(wv * 16 + n) * 40 + q * 8];
#pragma unroll
        for (int nt = 0; nt < 4; ++nt) {
            bf16x8 bv = *(const bf16x8*)&Bs[(nt * 16 + n) * 40 + q * 8];
            dot[nt] = __builtin_amdgcn_mfma_f32_16x16x32_bf16(av, bv, dot[nt], 0, 0, 0);
        }
        __syncthreads();
    }
    int base_row = i0 + wv * 16 + q * 4;
    float nA[4], pA[4]; int cA[4];
#pragma unroll
    for (int r = 0; r < 4; ++r) {
        nA[r] = norms[b * 512 + base_row + r];
        pA[r] = pa[b * 512 + base_row + r];
        cA[r] = argA[b * 512 + base_row + r];
    }
    float part = 0.f;
#pragma unroll
    for (int nt = 0; nt < 4; ++nt) {
        int col = j0 + nt * 16 + n;
        float nB = norms[32768 + b * 512 + col];
        float pB = pb[b * 512 + col];
        int cB = argB[b * 512 + col];
#pragma unroll
        for (int r = 0; r < 4; ++r) {
            float d2 = nA[r] + nB - 2.f * dot[nt][r];
            float c = sqrtf(fmaxf(d2, 0.f));
            float pm = pA[r] * pB;
            float cc = c + (BIGF - BIGF * pm);
            float sgn = (cA[r] == cB) ? 1.f : -1.f;
            part += cc * sgn * pm;
            Kb16[((size_t)b * 512 + base_row + r) * 512 + col] = f2bf(expf(-2.f * cc));
        }
    }
    float tot = block_reduce_256(part);
    if (threadIdx.x == 0) atomicAdd(&acc[ACC_IN + b], tot);
}

// LDS-resident Sinkhorn: 4 blocks per batch, each owns 128 rows of K in LDS.
// u-step is block-local (u_i consumed only by the row owner); only the 512-float
// partial column sums cross blocks, via gcp + a device-scope 4-block barrier.
// Launched cooperatively (256 blocks, 1 block/CU by LDS) so the spin barrier is safe.
__global__ __launch_bounds__(1024) void sinkhorn_kernel(
    const unsigned short* __restrict__ Kb16, float* __restrict__ u, float* __restrict__ v,
    float* __restrict__ gcp, unsigned int* __restrict__ bar) {
    const int b = (int)blockIdx.x >> 2;      // batch
    const int rq = (int)blockIdx.x & 3;      // row quarter (128 rows)
    const unsigned short* Kblk = Kb16 + (size_t)b * 262144 + (size_t)rq * 128 * 512;
    __shared__ unsigned short Ks[128 * 512];  // 128 KiB: our 128 rows of K
    __shared__ float cp[4][512];              // per-rowgroup partial col sums
    __shared__ float uv[128], vv[512];
    const int t = threadIdx.x;
    // load K slice into LDS: 16384 uint4
    {
        const uint4* src = (const uint4*)Kblk;
        uint4* dst = (uint4*)Ks;
#pragma unroll
        for (int p = 0; p < 16; ++p) dst[t + p * 1024] = src[t + p * 1024];
    }
    if (t < 128) uv[t] = 1.f / 512.f;
    __syncthreads();

    unsigned int target = 0;
    for (int it = 0; it < 10; ++it) {
        // ---- v-step partials: col sums over our 128 rows ----
        {
            int c2 = t & 255, rg = t >> 8;   // cols 2c2,2c2+1 ; rows rg*32..+32
            const unsigned short* base = Ks + (size_t)(rg * 32) * 512 + c2 * 2;
            float s0 = 0.f, s1 = 0.f;
#pragma unroll 8
            for (int i = 0; i < 32; ++i) {
                unsigned int w = *(const unsigned int*)(base + (size_t)i * 512);
                float ui = uv[rg * 32 + i];
                s0 = fmaf(__uint_as_float(w << 16), ui, s0);
                s1 = fmaf(__uint_as_float(w & 0xFFFF0000u), ui, s1);
            }
            *(float2*)&cp[rg][c2 * 2] = make_float2(s0, s1);
        }
        __syncthreads();
        // publish block partial (device-scope: per-XCD L2s are not coherent)
        float* slot = gcp + (size_t)((it & 1) * 64 + b) * 2048 + (size_t)rq * 512;
        if (t < 512) {
            float ps = cp[0][t] + cp[1][t] + cp[2][t] + cp[3][t];
            __hip_atomic_store(&slot[t], ps, __ATOMIC_RELAXED, __HIP_MEMORY_SCOPE_AGENT);
        }
        __syncthreads();
        // ---- 4-block barrier for batch b (monotonic counter, no reset) ----
        target += 4;
        if (t == 0) {
            __threadfence();
            __hip_atomic_fetch_add(&bar[b], 1u, __ATOMIC_ACQ_REL, __HIP_MEMORY_SCOPE_AGENT);
            while (__hip_atomic_load(&bar[b], __ATOMIC_ACQUIRE, __HIP_MEMORY_SCOPE_AGENT) < target)
                __builtin_amdgcn_s_sleep(1);
        }
        __syncthreads();
        // ---- combine 4 partials -> v (each block computes full v redundantly) ----
        {
            const float* pbuf = gcp + (size_t)((it & 1) * 64 + b) * 2048;
            if (t < 512) {
                float s = 0.f;
#pragma unroll
                for (int k = 0; k < 4; ++k)
                    s += __hip_atomic_load(&pbuf[k * 512 + t], __ATOMIC_RELAXED,
                                           __HIP_MEMORY_SCOPE_AGENT);
                vv[t] = (1.f / 512.f) / s;
            }
        }
        __syncthreads();
        // ---- u-step (local): 16 waves x 8 rows, row sums with v ----
        {
            int wv_ = t >> 6, l = t & 63;
            float vr[8];
            *(f32x4*)&vr[0] = *(const f32x4*)&vv[l * 8];
            *(f32x4*)&vr[4] = *(const f32x4*)&vv[l * 8 + 4];
#pragma unroll
            for (int rr = 0; rr < 8; ++rr) {
                int row = wv_ * 8 + rr;
                const unsigned int* rp = (const unsigned int*)&Ks[(size_t)row * 512 + l * 8];
                float s = 0.f;
#pragma unroll
                for (int c = 0; c < 4; ++c) {
                    unsigned int w = rp[c];
                    s = fmaf(__uint_as_float(w << 16), vr[c * 2], s);
                    s = fmaf(__uint_as_float(w & 0xFFFF0000u), vr[c * 2 + 1], s);
                }
#pragma unroll
                for (int off = 32; off > 0; off >>= 1) s += __shfl_down(s, off, 64);
                if (l == 0) uv[row] = (1.f / 512.f) / s;
            }
        }
        __syncthreads();
    }
    // write out: u from our rows; v from one block per batch
    if (t < 128) u[(size_t)b * 512 + rq * 128 + t] = uv[t];
    if (rq == 0 && t < 512) v[(size_t)b * 512 + t] = vv[t];
}

// sup loss on bf16 K
__global__ __launch_bounds__(256) void sup_kernel(
    const unsigned short* __restrict__ Kb16, const float* __restrict__ u,
    const float* __restrict__ v, const float* __restrict__ rel,
    const float* __restrict__ pa, float* __restrict__ acc) {
    const int nthreads = 4096 * 256;
    int tid = blockIdx.x * 256 + threadIdx.x;
    float part = 0.f;
#pragma unroll
    for (int k = 0; k < 4; ++k) {
        int i4 = tid + k * nthreads;
        int e = i4 * 4;
        int b = e >> 18;
        int i = (e >> 9) & 511;
        int j0 = e & 511;
        ushort4 K4 = *(const ushort4*)&Kb16[(size_t)i4 * 4];
        float4 r4 = *(const float4*)&rel[(size_t)i4 * 4];
        float4 v4 = *(const float4*)&v[b * 512 + j0];
        float ui = u[b * 512 + i] * 512.f;
        float pai = pa[b * 512 + i];
        float d0 = ui * bf2f(K4.x) * v4.x - r4.x;
        float d1 = ui * bf2f(K4.y) * v4.y - r4.y;
        float d2 = ui * bf2f(K4.z) * v4.z - r4.z;
        float d3 = ui * bf2f(K4.w) * v4.w - r4.w;
        part += (d0 * d0 + d1 * d1 + d2 * d2 + d3 * d3) * pai;
    }
    float tot = block_reduce_256(part);
    if (threadIdx.x == 0) atomicAdd(&acc[ACC_SUP + (blockIdx.x & 255)], tot);
}

__global__ __launch_bounds__(256) void final_kernel(const float* __restrict__ acc,
                                                    float* __restrict__ out) {
    int t = threadIdx.x;
    float vin = (t < 64) ? acc[ACC_IN + t] : 0.f;
    float sIn = block_reduce_256(vin);
    float vsup = acc[ACC_SUP + t];
    float sSup = block_reduce_256(vsup);
    if (t == 0)
        out[0] = sIn * (1.f / 16777216.f) + 10.f * sSup / acc[ACC_PA];
}

extern "C" void kernel_launch(void* const* d_in, const int* in_sizes, int n_in,
                              void* d_out, int out_size, void* d_ws, size_t ws_size,
                              hipStream_t stream) {
    const float* la  = (const float*)d_in[0];
    const float* lb  = (const float*)d_in[1];
    const float* xA  = (const float*)d_in[2];
    const float* xB  = (const float*)d_in[3];
    const float* rel = (const float*)d_in[4];
    const float* pa  = (const float*)d_in[5];
    const float* pb  = (const float*)d_in[6];
    const float* W1  = (const float*)d_in[7];
    const float* b1  = (const float*)d_in[8];
    const float* g1  = (const float*)d_in[9];
    const float* be1 = (const float*)d_in[10];
    const float* W2  = (const float*)d_in[11];
    const float* b2  = (const float*)d_in[12];
    const float* g2  = (const float*)d_in[13];
    const float* be2 = (const float*)d_in[14];
    float* out = (float*)d_out;

    float* ws = (float*)d_ws;
    unsigned short* Kb16 = (unsigned short*)(ws + KB_OFF);   // Ybf1/Ybf2 then K
    unsigned short* Xbf  = (unsigned short*)(ws + X_OFF);    // Xbf then Ebf
    unsigned short* Hbf  = (unsigned short*)(ws + H_OFF);
    float* norms = ws + NORM_OFF;
    float* u     = ws + U_OFF;
    float* v     = ws + V_OFF;
    int* argA    = (int*)(ws + ARGA_OFF);
    int* argB    = (int*)(ws + ARGB_OFF);
    float* acc   = ws + ACC_OFF;
    unsigned short* Wt1 = (unsigned short*)(ws + WT1_OFF);
    unsigned short* Wt2 = (unsigned short*)(ws + WT2_OFF);
    // sinkhorn exchange buffers: H region is dead after gemm2
    float* gcp = ws + H_OFF;                                  // [2][64][4][512] f32
    unsigned int* bar = (unsigned int*)(acc + BAR_IDX);       // 64 counters, zeroed by zero_acc

    zero_acc_kernel<<<2, 256, 0, stream>>>(acc);
    argmax_pa_kernel<<<128, 256, 0, stream>>>(la, lb, pa, argA, argB, acc);

    // casts
    cast_bf_kernel<<<2048, 256, 0, stream>>>(xA, Xbf);
    cast_bf_kernel<<<2048, 256, 0, stream>>>(xB, Xbf + (size_t)MROWS * DIM);
    cast_wt_kernel<<<dim3(16, 16), 256, 0, stream>>>(W1, Wt1);
    cast_wt_kernel<<<dim3(16, 16), 256, 0, stream>>>(W2, Wt2);

    // layer 1
    gemm_bf_kernel<<<1024, 256, 0, stream>>>(Xbf, Wt1, Kb16);
    ln_bf_kernel<<<16384, 256, 0, stream>>>(Kb16, Hbf, b1, g1, be1, nullptr);
    // layer 2
    gemm_bf_kernel<<<1024, 256, 0, stream>>>(Hbf, Wt2, Kb16);
    ln_bf_kernel<<<16384, 256, 0, stream>>>(Kb16, Xbf, b2, g2, be2, norms);  // Ebf -> Xbf buf

    // cost + K (bf16)
    cost_mfma_kernel<<<dim3(8, 8, 64), 256, 0, stream>>>(Xbf, norms, argA, argB, pa, pb, Kb16, acc);

    // sinkhorn: 256 blocks (4 per batch), LDS-resident K, cooperative for co-residency
    {
        void* args[] = {(void*)&Kb16, (void*)&u, (void*)&v, (void*)&gcp, (void*)&bar};
        hipLaunchCooperativeKernel((const void*)sinkhorn_kernel, dim3(256), dim3(1024),
                                   args, 0, stream);
    }

    sup_kernel<<<4096, 256, 0, stream>>>(Kb16, u, v, rel, pa, acc);
    final_kernel<<<1, 256, 0, stream>>>(acc, out);
}

// Round 4
// 518.677 us; speedup vs baseline: 1.1019x; 1.1019x over previous
//
#include <hip/hip_runtime.h>
#include <math.h>

// Problem constants
#define BSZ 64
#define NPTS 512
#define DIM 256
#define MROWS 32768      // BSZ*NPTS
#define TOTROWS 65536
#define BIGF 1.0e9f

typedef __bf16 bf16x8 __attribute__((ext_vector_type(8)));
typedef float  f32x4  __attribute__((ext_vector_type(4)));

// ws layout (float offsets)
#define KB_OFF    0ull          // 8388608 floats as ushort[16777216]: Ybf1 -> Ybf2 -> K(bf16)
#define X_OFF     8388608ull    // 8388608 floats as ushort[16777216]: Xbf -> Ebf
#define H_OFF     16777216ull   // 8388608 floats as ushort[16777216]: Hbf
#define NORM_OFF  25165824ull   // 65536 f32
#define U_OFF     25231360ull   // 32768 f32
#define V_OFF     25264128ull   // 32768 f32
#define ARGA_OFF  25296896ull   // 32768 int
#define ARGB_OFF  25329664ull   // 32768 int
#define ACC_OFF   25362432ull   // 512 f32
#define WT1_OFF   25362944ull   // 32768 floats as ushort[65536]
#define WT2_OFF   25395712ull   // 32768 floats as ushort[65536]

#define ACC_PA   0
#define ACC_IN   1     // 64 slots
#define ACC_SUP  65    // 256 slots
#define ACC_CNT  321

__device__ __forceinline__ float bf2f(unsigned short h) {
    return __uint_as_float(((unsigned int)h) << 16);
}
__device__ __forceinline__ unsigned short f2bf(float f) {
    unsigned int u = __float_as_uint(f);
    u = (u + 0x7FFFu + ((u >> 16) & 1u)) >> 16;
    return (unsigned short)u;
}

// re-entrant
__device__ __forceinline__ float block_reduce_256(float val) {
    __shared__ float sh[4];
    int lane = threadIdx.x & 63;
    int wv = threadIdx.x >> 6;
    __syncthreads();
#pragma unroll
    for (int off = 32; off > 0; off >>= 1) val += __shfl_down(val, off, 64);
    if (lane == 0) sh[wv] = val;
    __syncthreads();
    float r = 0.f;
    if (wv == 0 && lane < 4) r = sh[lane];
    if (wv == 0) {
        r += __shfl_down(r, 2, 64);
        r += __shfl_down(r, 1, 64);
    }
    return r;  // valid in thread 0
}

__global__ void zero_acc_kernel(float* acc) {
    int t = blockIdx.x * 256 + threadIdx.x;
    if (t < 512) acc[t] = 0.f;
}

__global__ __launch_bounds__(256) void argmax_pa_kernel(
    const float* __restrict__ la, const float* __restrict__ lb,
    const float* __restrict__ pa, int* __restrict__ argA, int* __restrict__ argB,
    float* __restrict__ acc) {
    int i = blockIdx.x * 256 + threadIdx.x;
    float4 a = *(const float4*)&la[(size_t)i * 4];
    float av[4] = {a.x, a.y, a.z, a.w};
    int ba = 0; float bv = av[0];
#pragma unroll
    for (int c = 1; c < 4; ++c) if (av[c] > bv) { bv = av[c]; ba = c; }
    argA[i] = ba;
    float4 b = *(const float4*)&lb[(size_t)i * 4];
    float bw[4] = {b.x, b.y, b.z, b.w};
    int bbi = 0; float bm = bw[0];
#pragma unroll
    for (int c = 1; c < 4; ++c) if (bw[c] > bm) { bm = bw[c]; bbi = c; }
    argB[i] = bbi;
    float p = pa[i];
#pragma unroll
    for (int off = 32; off > 0; off >>= 1) p += __shfl_down(p, off, 64);
    if ((threadIdx.x & 63) == 0) atomicAdd(&acc[ACC_PA], p);
}

// f32 -> bf16 bulk cast; grid 2048x256, 4 float4-groups/thread
__global__ __launch_bounds__(256) void cast_bf_kernel(
    const float* __restrict__ src, unsigned short* __restrict__ dst) {
    int tid = blockIdx.x * 256 + threadIdx.x;      // < 524288
#pragma unroll
    for (int k = 0; k < 4; ++k) {
        int i4 = tid + k * 524288;                 // < 2097152
        float4 v = *(const float4*)&src[(size_t)i4 * 4];
        ushort4 o;
        o.x = f2bf(v.x); o.y = f2bf(v.y); o.z = f2bf(v.z); o.w = f2bf(v.w);
        *(ushort4*)&dst[(size_t)i4 * 4] = o;
    }
}

// W[256][256] f32 -> Wt[n][k] bf16 (transposed)
__global__ __launch_bounds__(256) void cast_wt_kernel(
    const float* __restrict__ W, unsigned short* __restrict__ Wt) {
    __shared__ float tile[16][17];
    int tx = threadIdx.x & 15, ty = threadIdx.x >> 4;
    int bx = blockIdx.x, by = blockIdx.y;
    tile[ty][tx] = W[(size_t)(by * 16 + ty) * 256 + bx * 16 + tx];
    __syncthreads();
    Wt[(size_t)(bx * 16 + ty) * 256 + by * 16 + tx] = f2bf(tile[tx][ty]);
}

// Y(bf16) = X(bf16, Mx256) @ W via Wt (bf16, transposed [n][k])
__global__ __launch_bounds__(256) void gemm_bf_kernel(
    const unsigned short* __restrict__ X, const unsigned short* __restrict__ Wt,
    unsigned short* __restrict__ Y) {
    __shared__ unsigned short Xs[64 * 40];
    __shared__ unsigned short Ws[256 * 40];
    const int t = threadIdx.x;
    const int L = t & 63, wv = t >> 6;
    const int q = L >> 4, n = L & 15;
    const size_t row0 = (size_t)blockIdx.x * 64;
    f32x4 acc[16];
#pragma unroll
    for (int nt = 0; nt < 16; ++nt) acc[nt] = (f32x4){0.f, 0.f, 0.f, 0.f};

    for (int k0 = 0; k0 < 256; k0 += 32) {
        {
            int r = t >> 2, seg = t & 3;
            *(uint4*)&Xs[r * 40 + seg * 8] =
                *(const uint4*)&X[(row0 + r) * 256 + k0 + seg * 8];
#pragma unroll
            for (int it = 0; it < 4; ++it) {
                int nn = (t >> 2) + it * 64;
                *(uint4*)&Ws[nn * 40 + seg * 8] =
                    *(const uint4*)&Wt[(size_t)nn * 256 + k0 + seg * 8];
            }
        }
        __syncthreads();
        bf16x8 av = *(const bf16x8*)&Xs[(wv * 16 + n) * 40 + q * 8];
#pragma unroll
        for (int nt = 0; nt < 16; ++nt) {
            bf16x8 bv = *(const bf16x8*)&Ws[(nt * 16 + n) * 40 + q * 8];
            acc[nt] = __builtin_amdgcn_mfma_f32_16x16x32_bf16(av, bv, acc[nt], 0, 0, 0);
        }
        __syncthreads();
    }
#pragma unroll
    for (int nt = 0; nt < 16; ++nt)
#pragma unroll
        for (int r = 0; r < 4; ++r) {
            size_t row = row0 + wv * 16 + q * 4 + r;
            Y[row * 256 + nt * 16 + n] = f2bf(acc[nt][r]);
        }
}

// y_bf16_out = LN(leaky_relu(y_bf16_in + bias)) * g + be ; optional row sq-norms
__global__ __launch_bounds__(256) void ln_bf_kernel(
    const unsigned short* __restrict__ Yin, unsigned short* __restrict__ Yout,
    const float* __restrict__ bias, const float* __restrict__ gam,
    const float* __restrict__ bet, float* __restrict__ norms) {
    int lane = threadIdx.x & 63;
    int wv = threadIdx.x >> 6;
    size_t row = (size_t)blockIdx.x * 4 + wv;
    ushort4 y4 = *(const ushort4*)&Yin[row * 256 + lane * 4];
    float4 b4 = *(const float4*)&bias[lane * 4];
    float h[4] = {bf2f(y4.x) + b4.x, bf2f(y4.y) + b4.y, bf2f(y4.z) + b4.z, bf2f(y4.w) + b4.w};
#pragma unroll
    for (int e = 0; e < 4; ++e) h[e] = h[e] >= 0.f ? h[e] : 0.01f * h[e];
    float s = h[0] + h[1] + h[2] + h[3];
    float sq = h[0] * h[0] + h[1] * h[1] + h[2] * h[2] + h[3] * h[3];
#pragma unroll
    for (int off = 32; off > 0; off >>= 1) {
        s += __shfl_down(s, off, 64);
        sq += __shfl_down(sq, off, 64);
    }
    s = __shfl(s, 0, 64); sq = __shfl(sq, 0, 64);
    float mean = s * (1.f / 256.f);
    float var = fmaxf(sq * (1.f / 256.f) - mean * mean, 0.f);
    float inv = rsqrtf(var + 1e-5f);
    float4 g4 = *(const float4*)&gam[lane * 4];
    float4 e4 = *(const float4*)&bet[lane * 4];
    float gv[4] = {g4.x, g4.y, g4.z, g4.w};
    float ev[4] = {e4.x, e4.y, e4.z, e4.w};
    ushort4 o4; float nr = 0.f;
    {
        unsigned short ob[4];
#pragma unroll
        for (int e = 0; e < 4; ++e) {
            float o = (h[e] - mean) * inv * gv[e] + ev[e];
            ob[e] = f2bf(o);
            float orr = bf2f(ob[e]);
            nr += orr * orr;
        }
        o4.x = ob[0]; o4.y = ob[1]; o4.z = ob[2]; o4.w = ob[3];
    }
    *(ushort4*)&Yout[row * 256 + lane * 4] = o4;
    if (norms) {
#pragma unroll
        for (int off = 32; off > 0; off >>= 1) nr += __shfl_down(nr, off, 64);
        if (lane == 0) norms[row] = nr;
    }
}

// cdist via MFMA + in/out loss partial + K(bf16) = exp(-2*cost)
__global__ __launch_bounds__(256) void cost_mfma_kernel(
    const unsigned short* __restrict__ E, const float* __restrict__ norms,
    const int* __restrict__ argA, const int* __restrict__ argB,
    const float* __restrict__ pa, const float* __restrict__ pb,
    unsigned short* __restrict__ Kb16, float* __restrict__ acc) {
    __shared__ unsigned short As[64 * 40];
    __shared__ unsigned short Bs[64 * 40];
    const int t = threadIdx.x;
    const int L = t & 63, wv = t >> 6;
    const int q = L >> 4, n = L & 15;
    const int b = blockIdx.z;
    const int i0 = blockIdx.y * 64, j0 = blockIdx.x * 64;
    const unsigned short* eA = E + (size_t)b * 512 * 256;
    const unsigned short* eB = E + (size_t)(32768 + b * 512) * 256;
    f32x4 dot[4];
#pragma unroll
    for (int nt = 0; nt < 4; ++nt) dot[nt] = (f32x4){0.f, 0.f, 0.f, 0.f};

    for (int k0 = 0; k0 < 256; k0 += 32) {
        int r = t >> 2, seg = t & 3;
        *(uint4*)&As[r * 40 + seg * 8] =
            *(const uint4*)&eA[(size_t)(i0 + r) * 256 + k0 + seg * 8];
        *(uint4*)&Bs[r * 40 + seg * 8] =
            *(const uint4*)&eB[(size_t)(j0 + r) * 256 + k0 + seg * 8];
        __syncthreads();
        bf16x8 av = *(const bf16x8*)&As[(wv * 16 + n) * 40 + q * 8];
#pragma unroll
        for (int nt = 0; nt < 4; ++nt) {
            bf16x8 bv = *(const bf16x8*)&Bs[(nt * 16 + n) * 40 + q * 8];
            dot[nt] = __builtin_amdgcn_mfma_f32_16x16x32_bf16(av, bv, dot[nt], 0, 0, 0);
        }
        __syncthreads();
    }
    int base_row = i0 + wv * 16 + q * 4;
    float nA[4], pA[4]; int cA[4];
#pragma unroll
    for (int r = 0; r < 4; ++r) {
        nA[r] = norms[b * 512 + base_row + r];
        pA[r] = pa[b * 512 + base_row + r];
        cA[r] = argA[b * 512 + base_row + r];
    }
    float part = 0.f;
#pragma unroll
    for (int nt = 0; nt < 4; ++nt) {
        int col = j0 + nt * 16 + n;
        float nB = norms[32768 + b * 512 + col];
        float pB = pb[b * 512 + col];
        int cB = argB[b * 512 + col];
#pragma unroll
        for (int r = 0; r < 4; ++r) {
            float d2 = nA[r] + nB - 2.f * dot[nt][r];
            float c = sqrtf(fmaxf(d2, 0.f));
            float pm = pA[r] * pB;
            float cc = c + (BIGF - BIGF * pm);
            float sgn = (cA[r] == cB) ? 1.f : -1.f;
            part += cc * sgn * pm;
            Kb16[((size_t)b * 512 + base_row + r) * 512 + col] = f2bf(expf(-2.f * cc));
        }
    }
    float tot = block_reduce_256(part);
    if (threadIdx.x == 0) atomicAdd(&acc[ACC_IN + b], tot);
}

// Sinkhorn: one block per batch, NO cross-block sync. Both passes read K
// row-major COALESCED (one dwordx4 per lane covers a full 1024B row).
// v-step: per-lane column partials (lane l owns cols l*8..l*8+7), combined
// through a 16x512 LDS buffer. u-step: per-row shuffle reduce.
__global__ __launch_bounds__(1024) void sinkhorn_kernel(
    const unsigned short* __restrict__ Kb16, float* __restrict__ u, float* __restrict__ v) {
    const int b = blockIdx.x;
    const unsigned short* Kb = Kb16 + (size_t)b * 262144;
    __shared__ float uv[512], vv[512];
    __shared__ float cp[16][512];         // per-wave column partials (32 KiB)
    const int t = threadIdx.x, wv = t >> 6, l = t & 63;
    const unsigned short* base = Kb + (size_t)(wv * 32) * 512 + l * 8;  // our 32 rows
    if (t < 512) uv[t] = 1.f / 512.f;
    __syncthreads();

    for (int it = 0; it < 10; ++it) {
        // ---- v-step: col sums, coalesced ----
        float s[8];
#pragma unroll
        for (int e = 0; e < 8; ++e) s[e] = 0.f;
#pragma unroll 4
        for (int i = 0; i < 32; ++i) {
            uint4 w = *(const uint4*)(base + (size_t)i * 512);
            float ui = uv[wv * 32 + i];
            s[0] = fmaf(__uint_as_float(w.x << 16), ui, s[0]);
            s[1] = fmaf(__uint_as_float(w.x & 0xFFFF0000u), ui, s[1]);
            s[2] = fmaf(__uint_as_float(w.y << 16), ui, s[2]);
            s[3] = fmaf(__uint_as_float(w.y & 0xFFFF0000u), ui, s[3]);
            s[4] = fmaf(__uint_as_float(w.z << 16), ui, s[4]);
            s[5] = fmaf(__uint_as_float(w.z & 0xFFFF0000u), ui, s[5]);
            s[6] = fmaf(__uint_as_float(w.w << 16), ui, s[6]);
            s[7] = fmaf(__uint_as_float(w.w & 0xFFFF0000u), ui, s[7]);
        }
        *(f32x4*)&cp[wv][l * 8]     = *(f32x4*)&s[0];
        *(f32x4*)&cp[wv][l * 8 + 4] = *(f32x4*)&s[4];
        __syncthreads();
        if (t < 512) {
            float ss = 0.f;
#pragma unroll
            for (int k = 0; k < 16; ++k) ss += cp[k][t];
            vv[t] = (1.f / 512.f) / ss;
        }
        __syncthreads();
        // ---- u-step: row sums, coalesced ----
        float vr[8];
        *(f32x4*)&vr[0] = *(const f32x4*)&vv[l * 8];
        *(f32x4*)&vr[4] = *(const f32x4*)&vv[l * 8 + 4];
#pragma unroll 4
        for (int i = 0; i < 32; ++i) {
            uint4 w = *(const uint4*)(base + (size_t)i * 512);
            float rs;
            rs = __uint_as_float(w.x << 16) * vr[0];
            rs = fmaf(__uint_as_float(w.x & 0xFFFF0000u), vr[1], rs);
            rs = fmaf(__uint_as_float(w.y << 16),          vr[2], rs);
            rs = fmaf(__uint_as_float(w.y & 0xFFFF0000u), vr[3], rs);
            rs = fmaf(__uint_as_float(w.z << 16),          vr[4], rs);
            rs = fmaf(__uint_as_float(w.z & 0xFFFF0000u), vr[5], rs);
            rs = fmaf(__uint_as_float(w.w << 16),          vr[6], rs);
            rs = fmaf(__uint_as_float(w.w & 0xFFFF0000u), vr[7], rs);
#pragma unroll
            for (int off = 32; off > 0; off >>= 1) rs += __shfl_down(rs, off, 64);
            if (l == 0) uv[wv * 32 + i] = (1.f / 512.f) / rs;
        }
        __syncthreads();
    }
    if (t < 512) {
        u[(size_t)b * 512 + t] = uv[t];
        v[(size_t)b * 512 + t] = vv[t];
    }
}

// sup loss on bf16 K
__global__ __launch_bounds__(256) void sup_kernel(
    const unsigned short* __restrict__ Kb16, const float* __restrict__ u,
    const float* __restrict__ v, const float* __restrict__ rel,
    const float* __restrict__ pa, float* __restrict__ acc) {
    const int nthreads = 4096 * 256;
    int tid = blockIdx.x * 256 + threadIdx.x;
    float part = 0.f;
#pragma unroll
    for (int k = 0; k < 4; ++k) {
        int i4 = tid + k * nthreads;
        int e = i4 * 4;
        int b = e >> 18;
        int i = (e >> 9) & 511;
        int j0 = e & 511;
        ushort4 K4 = *(const ushort4*)&Kb16[(size_t)i4 * 4];
        float4 r4 = *(const float4*)&rel[(size_t)i4 * 4];
        float4 v4 = *(const float4*)&v[b * 512 + j0];
        float ui = u[b * 512 + i] * 512.f;
        float pai = pa[b * 512 + i];
        float d0 = ui * bf2f(K4.x) * v4.x - r4.x;
        float d1 = ui * bf2f(K4.y) * v4.y - r4.y;
        float d2 = ui * bf2f(K4.z) * v4.z - r4.z;
        float d3 = ui * bf2f(K4.w) * v4.w - r4.w;
        part += (d0 * d0 + d1 * d1 + d2 * d2 + d3 * d3) * pai;
    }
    float tot = block_reduce_256(part);
    if (threadIdx.x == 0) atomicAdd(&acc[ACC_SUP + (blockIdx.x & 255)], tot);
}

__global__ __launch_bounds__(256) void final_kernel(const float* __restrict__ acc,
                                                    float* __restrict__ out) {
    int t = threadIdx.x;
    float vin = (t < 64) ? acc[ACC_IN + t] : 0.f;
    float sIn = block_reduce_256(vin);
    float vsup = acc[ACC_SUP + t];
    float sSup = block_reduce_256(vsup);
    if (t == 0)
        out[0] = sIn * (1.f / 16777216.f) + 10.f * sSup / acc[ACC_PA];
}

extern "C" void kernel_launch(void* const* d_in, const int* in_sizes, int n_in,
                              void* d_out, int out_size, void* d_ws, size_t ws_size,
                              hipStream_t stream) {
    const float* la  = (const float*)d_in[0];
    const float* lb  = (const float*)d_in[1];
    const float* xA  = (const float*)d_in[2];
    const float* xB  = (const float*)d_in[3];
    const float* rel = (const float*)d_in[4];
    const float* pa  = (const float*)d_in[5];
    const float* pb  = (const float*)d_in[6];
    const float* W1  = (const float*)d_in[7];
    const float* b1  = (const float*)d_in[8];
    const float* g1  = (const float*)d_in[9];
    const float* be1 = (const float*)d_in[10];
    const float* W2  = (const float*)d_in[11];
    const float* b2  = (const float*)d_in[12];
    const float* g2  = (const float*)d_in[13];
    const float* be2 = (const float*)d_in[14];
    float* out = (float*)d_out;

    float* ws = (float*)d_ws;
    unsigned short* Kb16 = (unsigned short*)(ws + KB_OFF);   // Ybf1/Ybf2 then K
    unsigned short* Xbf  = (unsigned short*)(ws + X_OFF);    // Xbf then Ebf
    unsigned short* Hbf  = (unsigned short*)(ws + H_OFF);
    float* norms = ws + NORM_OFF;
    float* u     = ws + U_OFF;
    float* v     = ws + V_OFF;
    int* argA    = (int*)(ws + ARGA_OFF);
    int* argB    = (int*)(ws + ARGB_OFF);
    float* acc   = ws + ACC_OFF;
    unsigned short* Wt1 = (unsigned short*)(ws + WT1_OFF);
    unsigned short* Wt2 = (unsigned short*)(ws + WT2_OFF);

    zero_acc_kernel<<<2, 256, 0, stream>>>(acc);
    argmax_pa_kernel<<<128, 256, 0, stream>>>(la, lb, pa, argA, argB, acc);

    // casts
    cast_bf_kernel<<<2048, 256, 0, stream>>>(xA, Xbf);
    cast_bf_kernel<<<2048, 256, 0, stream>>>(xB, Xbf + (size_t)MROWS * DIM);
    cast_wt_kernel<<<dim3(16, 16), 256, 0, stream>>>(W1, Wt1);
    cast_wt_kernel<<<dim3(16, 16), 256, 0, stream>>>(W2, Wt2);

    // layer 1
    gemm_bf_kernel<<<1024, 256, 0, stream>>>(Xbf, Wt1, Kb16);
    ln_bf_kernel<<<16384, 256, 0, stream>>>(Kb16, Hbf, b1, g1, be1, nullptr);
    // layer 2
    gemm_bf_kernel<<<1024, 256, 0, stream>>>(Hbf, Wt2, Kb16);
    ln_bf_kernel<<<16384, 256, 0, stream>>>(Kb16, Xbf, b2, g2, be2, norms);  // Ebf -> Xbf buf

    // cost + K (bf16)
    cost_mfma_kernel<<<dim3(8, 8, 64), 256, 0, stream>>>(Xbf, norms, argA, argB, pa, pb, Kb16, acc);

    // sinkhorn: one block per batch, coalesced K passes, no cross-block sync
    sinkhorn_kernel<<<64, 1024, 0, stream>>>(Kb16, u, v);

    sup_kernel<<<4096, 256, 0, stream>>>(Kb16, u, v, rel, pa, acc);
    final_kernel<<<1, 256, 0, stream>>>(acc, out);
}

// Round 5
// 450.226 us; speedup vs baseline: 1.2695x; 1.1520x over previous
//
#include <hip/hip_runtime.h>
#include <math.h>

// Problem constants
#define BSZ 64
#define NPTS 512
#define DIM 256
#define MROWS 32768      // BSZ*NPTS
#define TOTROWS 65536
#define BIGF 1.0e9f

typedef __bf16 bf16x8 __attribute__((ext_vector_type(8)));
typedef float  f32x4  __attribute__((ext_vector_type(4)));

// ws layout (float offsets)
#define KB_OFF    0ull          // 8388608 floats as ushort[16777216]: Ybf1 -> Ybf2 -> K(bf16)
#define X_OFF     8388608ull    // 8388608 floats as ushort[16777216]: Xbf -> Ebf
#define H_OFF     16777216ull   // 8388608 floats as ushort[16777216]: Hbf
#define NORM_OFF  25165824ull   // 65536 f32
#define U_OFF     25231360ull   // 32768 f32
#define V_OFF     25264128ull   // 32768 f32
#define ARGA_OFF  25296896ull   // 32768 int
#define ARGB_OFF  25329664ull   // 32768 int
#define ACC_OFF   25362432ull   // 512 f32
#define WT1_OFF   25362944ull   // 32768 floats as ushort[65536]
#define WT2_OFF   25395712ull   // 32768 floats as ushort[65536]

#define ACC_PA   0
#define ACC_IN   1     // 64 slots
#define ACC_SUP  65    // 256 slots
#define ACC_CNT  321

__device__ __forceinline__ float bf2f(unsigned short h) {
    return __uint_as_float(((unsigned int)h) << 16);
}
__device__ __forceinline__ unsigned short f2bf(float f) {
    unsigned int u = __float_as_uint(f);
    u = (u + 0x7FFFu + ((u >> 16) & 1u)) >> 16;
    return (unsigned short)u;
}

// re-entrant
__device__ __forceinline__ float block_reduce_256(float val) {
    __shared__ float sh[4];
    int lane = threadIdx.x & 63;
    int wv = threadIdx.x >> 6;
    __syncthreads();
#pragma unroll
    for (int off = 32; off > 0; off >>= 1) val += __shfl_down(val, off, 64);
    if (lane == 0) sh[wv] = val;
    __syncthreads();
    float r = 0.f;
    if (wv == 0 && lane < 4) r = sh[lane];
    if (wv == 0) {
        r += __shfl_down(r, 2, 64);
        r += __shfl_down(r, 1, 64);
    }
    return r;  // valid in thread 0
}

__global__ void zero_acc_kernel(float* acc) {
    int t = blockIdx.x * 256 + threadIdx.x;
    if (t < 512) acc[t] = 0.f;
}

__global__ __launch_bounds__(256) void argmax_pa_kernel(
    const float* __restrict__ la, const float* __restrict__ lb,
    const float* __restrict__ pa, int* __restrict__ argA, int* __restrict__ argB,
    float* __restrict__ acc) {
    int i = blockIdx.x * 256 + threadIdx.x;
    float4 a = *(const float4*)&la[(size_t)i * 4];
    float av[4] = {a.x, a.y, a.z, a.w};
    int ba = 0; float bv = av[0];
#pragma unroll
    for (int c = 1; c < 4; ++c) if (av[c] > bv) { bv = av[c]; ba = c; }
    argA[i] = ba;
    float4 b = *(const float4*)&lb[(size_t)i * 4];
    float bw[4] = {b.x, b.y, b.z, b.w};
    int bbi = 0; float bm = bw[0];
#pragma unroll
    for (int c = 1; c < 4; ++c) if (bw[c] > bm) { bm = bw[c]; bbi = c; }
    argB[i] = bbi;
    float p = pa[i];
#pragma unroll
    for (int off = 32; off > 0; off >>= 1) p += __shfl_down(p, off, 64);
    if ((threadIdx.x & 63) == 0) atomicAdd(&acc[ACC_PA], p);
}

// f32 -> bf16 bulk cast; grid 2048x256, 4 float4-groups/thread
__global__ __launch_bounds__(256) void cast_bf_kernel(
    const float* __restrict__ src, unsigned short* __restrict__ dst) {
    int tid = blockIdx.x * 256 + threadIdx.x;      // < 524288
#pragma unroll
    for (int k = 0; k < 4; ++k) {
        int i4 = tid + k * 524288;                 // < 2097152
        float4 v = *(const float4*)&src[(size_t)i4 * 4];
        ushort4 o;
        o.x = f2bf(v.x); o.y = f2bf(v.y); o.z = f2bf(v.z); o.w = f2bf(v.w);
        *(ushort4*)&dst[(size_t)i4 * 4] = o;
    }
}

// W[256][256] f32 -> Wt[n][k] bf16 (transposed)
__global__ __launch_bounds__(256) void cast_wt_kernel(
    const float* __restrict__ W, unsigned short* __restrict__ Wt) {
    __shared__ float tile[16][17];
    int tx = threadIdx.x & 15, ty = threadIdx.x >> 4;
    int bx = blockIdx.x, by = blockIdx.y;
    tile[ty][tx] = W[(size_t)(by * 16 + ty) * 256 + bx * 16 + tx];
    __syncthreads();
    Wt[(size_t)(bx * 16 + ty) * 256 + by * 16 + tx] = f2bf(tile[tx][ty]);
}

// Y(bf16) = X(bf16, Mx256) @ W via Wt (bf16, transposed [n][k])
__global__ __launch_bounds__(256) void gemm_bf_kernel(
    const unsigned short* __restrict__ X, const unsigned short* __restrict__ Wt,
    unsigned short* __restrict__ Y) {
    __shared__ unsigned short Xs[64 * 40];
    __shared__ unsigned short Ws[256 * 40];
    const int t = threadIdx.x;
    const int L = t & 63, wv = t >> 6;
    const int q = L >> 4, n = L & 15;
    const size_t row0 = (size_t)blockIdx.x * 64;
    f32x4 acc[16];
#pragma unroll
    for (int nt = 0; nt < 16; ++nt) acc[nt] = (f32x4){0.f, 0.f, 0.f, 0.f};

    for (int k0 = 0; k0 < 256; k0 += 32) {
        {
            int r = t >> 2, seg = t & 3;
            *(uint4*)&Xs[r * 40 + seg * 8] =
                *(const uint4*)&X[(row0 + r) * 256 + k0 + seg * 8];
#pragma unroll
            for (int it = 0; it < 4; ++it) {
                int nn = (t >> 2) + it * 64;
                *(uint4*)&Ws[nn * 40 + seg * 8] =
                    *(const uint4*)&Wt[(size_t)nn * 256 + k0 + seg * 8];
            }
        }
        __syncthreads();
        bf16x8 av = *(const bf16x8*)&Xs[(wv * 16 + n) * 40 + q * 8];
#pragma unroll
        for (int nt = 0; nt < 16; ++nt) {
            bf16x8 bv = *(const bf16x8*)&Ws[(nt * 16 + n) * 40 + q * 8];
            acc[nt] = __builtin_amdgcn_mfma_f32_16x16x32_bf16(av, bv, acc[nt], 0, 0, 0);
        }
        __syncthreads();
    }
#pragma unroll
    for (int nt = 0; nt < 16; ++nt)
#pragma unroll
        for (int r = 0; r < 4; ++r) {
            size_t row = row0 + wv * 16 + q * 4 + r;
            Y[row * 256 + nt * 16 + n] = f2bf(acc[nt][r]);
        }
}

// y_bf16_out = LN(leaky_relu(y_bf16_in + bias)) * g + be ; optional row sq-norms
__global__ __launch_bounds__(256) void ln_bf_kernel(
    const unsigned short* __restrict__ Yin, unsigned short* __restrict__ Yout,
    const float* __restrict__ bias, const float* __restrict__ gam,
    const float* __restrict__ bet, float* __restrict__ norms) {
    int lane = threadIdx.x & 63;
    int wv = threadIdx.x >> 6;
    size_t row = (size_t)blockIdx.x * 4 + wv;
    ushort4 y4 = *(const ushort4*)&Yin[row * 256 + lane * 4];
    float4 b4 = *(const float4*)&bias[lane * 4];
    float h[4] = {bf2f(y4.x) + b4.x, bf2f(y4.y) + b4.y, bf2f(y4.z) + b4.z, bf2f(y4.w) + b4.w};
#pragma unroll
    for (int e = 0; e < 4; ++e) h[e] = h[e] >= 0.f ? h[e] : 0.01f * h[e];
    float s = h[0] + h[1] + h[2] + h[3];
    float sq = h[0] * h[0] + h[1] * h[1] + h[2] * h[2] + h[3] * h[3];
#pragma unroll
    for (int off = 32; off > 0; off >>= 1) {
        s += __shfl_down(s, off, 64);
        sq += __shfl_down(sq, off, 64);
    }
    s = __shfl(s, 0, 64); sq = __shfl(sq, 0, 64);
    float mean = s * (1.f / 256.f);
    float var = fmaxf(sq * (1.f / 256.f) - mean * mean, 0.f);
    float inv = rsqrtf(var + 1e-5f);
    float4 g4 = *(const float4*)&gam[lane * 4];
    float4 e4 = *(const float4*)&bet[lane * 4];
    float gv[4] = {g4.x, g4.y, g4.z, g4.w};
    float ev[4] = {e4.x, e4.y, e4.z, e4.w};
    ushort4 o4; float nr = 0.f;
    {
        unsigned short ob[4];
#pragma unroll
        for (int e = 0; e < 4; ++e) {
            float o = (h[e] - mean) * inv * gv[e] + ev[e];
            ob[e] = f2bf(o);
            float orr = bf2f(ob[e]);
            nr += orr * orr;
        }
        o4.x = ob[0]; o4.y = ob[1]; o4.z = ob[2]; o4.w = ob[3];
    }
    *(ushort4*)&Yout[row * 256 + lane * 4] = o4;
    if (norms) {
#pragma unroll
        for (int off = 32; off > 0; off >>= 1) nr += __shfl_down(nr, off, 64);
        if (lane == 0) norms[row] = nr;
    }
}

// cdist via MFMA + in/out loss partial + K(bf16) = exp(-2*cost)
__global__ __launch_bounds__(256) void cost_mfma_kernel(
    const unsigned short* __restrict__ E, const float* __restrict__ norms,
    const int* __restrict__ argA, const int* __restrict__ argB,
    const float* __restrict__ pa, const float* __restrict__ pb,
    unsigned short* __restrict__ Kb16, float* __restrict__ acc) {
    __shared__ unsigned short As[64 * 40];
    __shared__ unsigned short Bs[64 * 40];
    const int t = threadIdx.x;
    const int L = t & 63, wv = t >> 6;
    const int q = L >> 4, n = L & 15;
    const int b = blockIdx.z;
    const int i0 = blockIdx.y * 64, j0 = blockIdx.x * 64;
    const unsigned short* eA = E + (size_t)b * 512 * 256;
    const unsigned short* eB = E + (size_t)(32768 + b * 512) * 256;
    f32x4 dot[4];
#pragma unroll
    for (int nt = 0; nt < 4; ++nt) dot[nt] = (f32x4){0.f, 0.f, 0.f, 0.f};

    for (int k0 = 0; k0 < 256; k0 += 32) {
        int r = t >> 2, seg = t & 3;
        *(uint4*)&As[r * 40 + seg * 8] =
            *(const uint4*)&eA[(size_t)(i0 + r) * 256 + k0 + seg * 8];
        *(uint4*)&Bs[r * 40 + seg * 8] =
            *(const uint4*)&eB[(size_t)(j0 + r) * 256 + k0 + seg * 8];
        __syncthreads();
        bf16x8 av = *(const bf16x8*)&As[(wv * 16 + n) * 40 + q * 8];
#pragma unroll
        for (int nt = 0; nt < 4; ++nt) {
            bf16x8 bv = *(const bf16x8*)&Bs[(nt * 16 + n) * 40 + q * 8];
            dot[nt] = __builtin_amdgcn_mfma_f32_16x16x32_bf16(av, bv, dot[nt], 0, 0, 0);
        }
        __syncthreads();
    }
    int base_row = i0 + wv * 16 + q * 4;
    float nA[4], pA[4]; int cA[4];
#pragma unroll
    for (int r = 0; r < 4; ++r) {
        nA[r] = norms[b * 512 + base_row + r];
        pA[r] = pa[b * 512 + base_row + r];
        cA[r] = argA[b * 512 + base_row + r];
    }
    float part = 0.f;
#pragma unroll
    for (int nt = 0; nt < 4; ++nt) {
        int col = j0 + nt * 16 + n;
        float nB = norms[32768 + b * 512 + col];
        float pB = pb[b * 512 + col];
        int cB = argB[b * 512 + col];
#pragma unroll
        for (int r = 0; r < 4; ++r) {
            float d2 = nA[r] + nB - 2.f * dot[nt][r];
            float c = sqrtf(fmaxf(d2, 0.f));
            float pm = pA[r] * pB;
            float cc = c + (BIGF - BIGF * pm);
            float sgn = (cA[r] == cB) ? 1.f : -1.f;
            part += cc * sgn * pm;
            Kb16[((size_t)b * 512 + base_row + r) * 512 + col] = f2bf(expf(-2.f * cc));
        }
    }
    float tot = block_reduce_256(part);
    if (threadIdx.x == 0) atomicAdd(&acc[ACC_IN + b], tot);
}

// Fused Sinkhorn: one block per batch. Key identity: u_i(t) is complete as soon
// as row i's reduction over v(t) finishes, so the NEXT iteration's column
// partials S'_j += K_ij*u_i are accumulated in the SAME pass, reusing the same
// loaded+unpacked row. 11 passes over K total (1 col-sum + 9 fused + 1 row-only)
// instead of 20. Row reduce = 6x shfl_xor all-lanes butterfly (no broadcast).
__global__ __launch_bounds__(1024) void sinkhorn_kernel(
    const unsigned short* __restrict__ Kb16, float* __restrict__ u, float* __restrict__ v) {
    const int b = blockIdx.x;
    const unsigned short* Kb = Kb16 + (size_t)b * 262144;
    __shared__ float uv[512], vv[512];
    __shared__ float cp[16][512];         // per-wave column partials (32 KiB)
    const int t = threadIdx.x, wv = t >> 6, l = t & 63;
    const unsigned short* base = Kb + (size_t)(wv * 32) * 512 + l * 8;  // our 32 rows

    // ---- pass 0: col sums with uniform u0 -> v1_j = 1 / sum_i K_ij ----
    {
        float s[8];
#pragma unroll
        for (int e = 0; e < 8; ++e) s[e] = 0.f;
#pragma unroll 4
        for (int i = 0; i < 32; ++i) {
            uint4 w = *(const uint4*)(base + (size_t)i * 512);
            s[0] += __uint_as_float(w.x << 16);
            s[1] += __uint_as_float(w.x & 0xFFFF0000u);
            s[2] += __uint_as_float(w.y << 16);
            s[3] += __uint_as_float(w.y & 0xFFFF0000u);
            s[4] += __uint_as_float(w.z << 16);
            s[5] += __uint_as_float(w.z & 0xFFFF0000u);
            s[6] += __uint_as_float(w.w << 16);
            s[7] += __uint_as_float(w.w & 0xFFFF0000u);
        }
        *(f32x4*)&cp[wv][l * 8]     = *(f32x4*)&s[0];
        *(f32x4*)&cp[wv][l * 8 + 4] = *(f32x4*)&s[4];
        __syncthreads();
        if (t < 512) {
            float ss = 0.f;
#pragma unroll
            for (int k = 0; k < 16; ++k) ss += cp[k][t];
            vv[t] = 1.f / ss;                       // (1/512)/((1/512)*ss)
        }
        __syncthreads();
    }

    // ---- passes 1..9 (fused): u(t) from v(t); col partials for v(t+1) ----
    for (int it = 1; it <= 9; ++it) {
        float vr[8];
        *(f32x4*)&vr[0] = *(const f32x4*)&vv[l * 8];
        *(f32x4*)&vr[4] = *(const f32x4*)&vv[l * 8 + 4];
        float cs[8];
#pragma unroll
        for (int e = 0; e < 8; ++e) cs[e] = 0.f;
#pragma unroll 4
        for (int i = 0; i < 32; ++i) {
            uint4 w = *(const uint4*)(base + (size_t)i * 512);
            float k0 = __uint_as_float(w.x << 16);
            float k1 = __uint_as_float(w.x & 0xFFFF0000u);
            float k2 = __uint_as_float(w.y << 16);
            float k3 = __uint_as_float(w.y & 0xFFFF0000u);
            float k4 = __uint_as_float(w.z << 16);
            float k5 = __uint_as_float(w.z & 0xFFFF0000u);
            float k6 = __uint_as_float(w.w << 16);
            float k7 = __uint_as_float(w.w & 0xFFFF0000u);
            float rs = k0 * vr[0];
            rs = fmaf(k1, vr[1], rs); rs = fmaf(k2, vr[2], rs);
            rs = fmaf(k3, vr[3], rs); rs = fmaf(k4, vr[4], rs);
            rs = fmaf(k5, vr[5], rs); rs = fmaf(k6, vr[6], rs);
            rs = fmaf(k7, vr[7], rs);
#pragma unroll
            for (int off = 32; off > 0; off >>= 1) rs += __shfl_xor(rs, off, 64);
            float ui = 0.001953125f * __builtin_amdgcn_rcpf(rs);   // (1/512)/rs
            cs[0] = fmaf(k0, ui, cs[0]); cs[1] = fmaf(k1, ui, cs[1]);
            cs[2] = fmaf(k2, ui, cs[2]); cs[3] = fmaf(k3, ui, cs[3]);
            cs[4] = fmaf(k4, ui, cs[4]); cs[5] = fmaf(k5, ui, cs[5]);
            cs[6] = fmaf(k6, ui, cs[6]); cs[7] = fmaf(k7, ui, cs[7]);
        }
        *(f32x4*)&cp[wv][l * 8]     = *(f32x4*)&cs[0];
        *(f32x4*)&cp[wv][l * 8 + 4] = *(f32x4*)&cs[4];
        __syncthreads();
        if (t < 512) {
            float ss = 0.f;
#pragma unroll
            for (int k = 0; k < 16; ++k) ss += cp[k][t];
            vv[t] = (1.f / 512.f) / ss;
        }
        __syncthreads();
    }

    // ---- pass 10: u(10) from v(10), no col accumulation ----
    {
        float vr[8];
        *(f32x4*)&vr[0] = *(const f32x4*)&vv[l * 8];
        *(f32x4*)&vr[4] = *(const f32x4*)&vv[l * 8 + 4];
#pragma unroll 4
        for (int i = 0; i < 32; ++i) {
            uint4 w = *(const uint4*)(base + (size_t)i * 512);
            float rs = __uint_as_float(w.x << 16) * vr[0];
            rs = fmaf(__uint_as_float(w.x & 0xFFFF0000u), vr[1], rs);
            rs = fmaf(__uint_as_float(w.y << 16),          vr[2], rs);
            rs = fmaf(__uint_as_float(w.y & 0xFFFF0000u), vr[3], rs);
            rs = fmaf(__uint_as_float(w.z << 16),          vr[4], rs);
            rs = fmaf(__uint_as_float(w.z & 0xFFFF0000u), vr[5], rs);
            rs = fmaf(__uint_as_float(w.w << 16),          vr[6], rs);
            rs = fmaf(__uint_as_float(w.w & 0xFFFF0000u), vr[7], rs);
#pragma unroll
            for (int off = 32; off > 0; off >>= 1) rs += __shfl_xor(rs, off, 64);
            if (l == 0) uv[wv * 32 + i] = (1.f / 512.f) / rs;     // exact for output
        }
        __syncthreads();
    }
    if (t < 512) {
        u[(size_t)b * 512 + t] = uv[t];
        v[(size_t)b * 512 + t] = vv[t];
    }
}

// sup loss on bf16 K
__global__ __launch_bounds__(256) void sup_kernel(
    const unsigned short* __restrict__ Kb16, const float* __restrict__ u,
    const float* __restrict__ v, const float* __restrict__ rel,
    const float* __restrict__ pa, float* __restrict__ acc) {
    const int nthreads = 4096 * 256;
    int tid = blockIdx.x * 256 + threadIdx.x;
    float part = 0.f;
#pragma unroll
    for (int k = 0; k < 4; ++k) {
        int i4 = tid + k * nthreads;
        int e = i4 * 4;
        int b = e >> 18;
        int i = (e >> 9) & 511;
        int j0 = e & 511;
        ushort4 K4 = *(const ushort4*)&Kb16[(size_t)i4 * 4];
        float4 r4 = *(const float4*)&rel[(size_t)i4 * 4];
        float4 v4 = *(const float4*)&v[b * 512 + j0];
        float ui = u[b * 512 + i] * 512.f;
        float pai = pa[b * 512 + i];
        float d0 = ui * bf2f(K4.x) * v4.x - r4.x;
        float d1 = ui * bf2f(K4.y) * v4.y - r4.y;
        float d2 = ui * bf2f(K4.z) * v4.z - r4.z;
        float d3 = ui * bf2f(K4.w) * v4.w - r4.w;
        part += (d0 * d0 + d1 * d1 + d2 * d2 + d3 * d3) * pai;
    }
    float tot = block_reduce_256(part);
    if (threadIdx.x == 0) atomicAdd(&acc[ACC_SUP + (blockIdx.x & 255)], tot);
}

__global__ __launch_bounds__(256) void final_kernel(const float* __restrict__ acc,
                                                    float* __restrict__ out) {
    int t = threadIdx.x;
    float vin = (t < 64) ? acc[ACC_IN + t] : 0.f;
    float sIn = block_reduce_256(vin);
    float vsup = acc[ACC_SUP + t];
    float sSup = block_reduce_256(vsup);
    if (t == 0)
        out[0] = sIn * (1.f / 16777216.f) + 10.f * sSup / acc[ACC_PA];
}

extern "C" void kernel_launch(void* const* d_in, const int* in_sizes, int n_in,
                              void* d_out, int out_size, void* d_ws, size_t ws_size,
                              hipStream_t stream) {
    const float* la  = (const float*)d_in[0];
    const float* lb  = (const float*)d_in[1];
    const float* xA  = (const float*)d_in[2];
    const float* xB  = (const float*)d_in[3];
    const float* rel = (const float*)d_in[4];
    const float* pa  = (const float*)d_in[5];
    const float* pb  = (const float*)d_in[6];
    const float* W1  = (const float*)d_in[7];
    const float* b1  = (const float*)d_in[8];
    const float* g1  = (const float*)d_in[9];
    const float* be1 = (const float*)d_in[10];
    const float* W2  = (const float*)d_in[11];
    const float* b2  = (const float*)d_in[12];
    const float* g2  = (const float*)d_in[13];
    const float* be2 = (const float*)d_in[14];
    float* out = (float*)d_out;

    float* ws = (float*)d_ws;
    unsigned short* Kb16 = (unsigned short*)(ws + KB_OFF);   // Ybf1/Ybf2 then K
    unsigned short* Xbf  = (unsigned short*)(ws + X_OFF);    // Xbf then Ebf
    unsigned short* Hbf  = (unsigned short*)(ws + H_OFF);
    float* norms = ws + NORM_OFF;
    float* u     = ws + U_OFF;
    float* v     = ws + V_OFF;
    int* argA    = (int*)(ws + ARGA_OFF);
    int* argB    = (int*)(ws + ARGB_OFF);
    float* acc   = ws + ACC_OFF;
    unsigned short* Wt1 = (unsigned short*)(ws + WT1_OFF);
    unsigned short* Wt2 = (unsigned short*)(ws + WT2_OFF);

    zero_acc_kernel<<<2, 256, 0, stream>>>(acc);
    argmax_pa_kernel<<<128, 256, 0, stream>>>(la, lb, pa, argA, argB, acc);

    // casts
    cast_bf_kernel<<<2048, 256, 0, stream>>>(xA, Xbf);
    cast_bf_kernel<<<2048, 256, 0, stream>>>(xB, Xbf + (size_t)MROWS * DIM);
    cast_wt_kernel<<<dim3(16, 16), 256, 0, stream>>>(W1, Wt1);
    cast_wt_kernel<<<dim3(16, 16), 256, 0, stream>>>(W2, Wt2);

    // layer 1
    gemm_bf_kernel<<<1024, 256, 0, stream>>>(Xbf, Wt1, Kb16);
    ln_bf_kernel<<<16384, 256, 0, stream>>>(Kb16, Hbf, b1, g1, be1, nullptr);
    // layer 2
    gemm_bf_kernel<<<1024, 256, 0, stream>>>(Hbf, Wt2, Kb16);
    ln_bf_kernel<<<16384, 256, 0, stream>>>(Kb16, Xbf, b2, g2, be2, norms);  // Ebf -> Xbf buf

    // cost + K (bf16)
    cost_mfma_kernel<<<dim3(8, 8, 64), 256, 0, stream>>>(Xbf, norms, argA, argB, pa, pb, Kb16, acc);

    // sinkhorn: one block per batch, fused passes (11 K-passes instead of 20)
    sinkhorn_kernel<<<64, 1024, 0, stream>>>(Kb16, u, v);

    sup_kernel<<<4096, 256, 0, stream>>>(Kb16, u, v, rel, pa, acc);
    final_kernel<<<1, 256, 0, stream>>>(acc, out);
}

// Round 6
// 405.620 us; speedup vs baseline: 1.4091x; 1.1100x over previous
//
#include <hip/hip_runtime.h>
#include <math.h>

// Problem constants
#define BSZ 64
#define NPTS 512
#define DIM 256
#define MROWS 32768      // BSZ*NPTS
#define TOTROWS 65536
#define BIGF 1.0e9f

typedef __bf16 bf16x8 __attribute__((ext_vector_type(8)));
typedef float  f32x4  __attribute__((ext_vector_type(4)));

// ws layout (float offsets)
#define KB_OFF    0ull          // 8388608 floats as ushort[16777216]: Ybf1 -> Ybf2 -> K(bf16)
#define X_OFF     8388608ull    // 8388608 floats as ushort[16777216]: Xbf -> Ebf
#define H_OFF     16777216ull   // 8388608 floats as ushort[16777216]: Hbf
#define NORM_OFF  25165824ull   // 65536 f32
#define U_OFF     25231360ull   // 32768 f32 (colsum staged here pre-sinkhorn)
#define V_OFF     25264128ull   // 32768 f32
#define ARGA_OFF  25296896ull   // 32768 int
#define ARGB_OFF  25329664ull   // 32768 int
#define ACC_OFF   25362432ull   // 512 f32
#define WT1_OFF   25362944ull   // 32768 floats as ushort[65536]
#define WT2_OFF   25395712ull   // 32768 floats as ushort[65536]

#define ACC_PA   0
#define ACC_IN   1     // 64 slots
#define ACC_SUP  65    // 256 slots
#define ACC_CNT  321

__device__ __forceinline__ float bf2f(unsigned short h) {
    return __uint_as_float(((unsigned int)h) << 16);
}
__device__ __forceinline__ unsigned short f2bf(float f) {
    unsigned int u = __float_as_uint(f);
    u = (u + 0x7FFFu + ((u >> 16) & 1u)) >> 16;
    return (unsigned short)u;
}

// re-entrant
__device__ __forceinline__ float block_reduce_256(float val) {
    __shared__ float sh[4];
    int lane = threadIdx.x & 63;
    int wv = threadIdx.x >> 6;
    __syncthreads();
#pragma unroll
    for (int off = 32; off > 0; off >>= 1) val += __shfl_down(val, off, 64);
    if (lane == 0) sh[wv] = val;
    __syncthreads();
    float r = 0.f;
    if (wv == 0 && lane < 4) r = sh[lane];
    if (wv == 0) {
        r += __shfl_down(r, 2, 64);
        r += __shfl_down(r, 1, 64);
    }
    return r;  // valid in thread 0
}

__device__ __forceinline__ void unpack8(uint4 w, float* k) {
    k[0] = __uint_as_float(w.x << 16);
    k[1] = __uint_as_float(w.x & 0xFFFF0000u);
    k[2] = __uint_as_float(w.y << 16);
    k[3] = __uint_as_float(w.y & 0xFFFF0000u);
    k[4] = __uint_as_float(w.z << 16);
    k[5] = __uint_as_float(w.z & 0xFFFF0000u);
    k[6] = __uint_as_float(w.w << 16);
    k[7] = __uint_as_float(w.w & 0xFFFF0000u);
}
__device__ __forceinline__ float dot8(const float* k, const float* vr) {
    float rs = k[0] * vr[0];
    rs = fmaf(k[1], vr[1], rs); rs = fmaf(k[2], vr[2], rs);
    rs = fmaf(k[3], vr[3], rs); rs = fmaf(k[4], vr[4], rs);
    rs = fmaf(k[5], vr[5], rs); rs = fmaf(k[6], vr[6], rs);
    return fmaf(k[7], vr[7], rs);
}

// Packed 4-row all-lanes reduce: rows A,B,C,D per-lane partials -> row sums,
// replicated within 16-lane groups: g0=A, g1=C, g2=B, g3=D. 10 DS ops for 4 rows.
__device__ __forceinline__ float packed_reduce4(float p0, float p1, float p2, float p3, int l) {
    p0 += __shfl_xor(p0, 32, 64);
    p1 += __shfl_xor(p1, 32, 64);
    p2 += __shfl_xor(p2, 32, 64);
    p3 += __shfl_xor(p3, 32, 64);
    float m1 = (l & 32) ? p1 : p0;
    float m2 = (l & 32) ? p3 : p2;
    m1 += __shfl_xor(m1, 16, 64);
    m2 += __shfl_xor(m2, 16, 64);
    float s = (l & 16) ? m2 : m1;
    s += __shfl_xor(s, 8, 64);
    s += __shfl_xor(s, 4, 64);
    s += __shfl_xor(s, 2, 64);
    s += __shfl_xor(s, 1, 64);
    return s;
}
__device__ __forceinline__ float bcast_lane(float x, int lane) {
    return __uint_as_float((unsigned)__builtin_amdgcn_readlane((int)__float_as_uint(x), lane));
}

__global__ void zero_acc_kernel(float* acc, float* colsum) {
    int t = blockIdx.x * 256 + threadIdx.x;   // grid 128*256 = 32768
    if (t < 512) acc[t] = 0.f;
    colsum[t] = 0.f;
}

__global__ __launch_bounds__(256) void argmax_pa_kernel(
    const float* __restrict__ la, const float* __restrict__ lb,
    const float* __restrict__ pa, int* __restrict__ argA, int* __restrict__ argB,
    float* __restrict__ acc) {
    int i = blockIdx.x * 256 + threadIdx.x;
    float4 a = *(const float4*)&la[(size_t)i * 4];
    float av[4] = {a.x, a.y, a.z, a.w};
    int ba = 0; float bv = av[0];
#pragma unroll
    for (int c = 1; c < 4; ++c) if (av[c] > bv) { bv = av[c]; ba = c; }
    argA[i] = ba;
    float4 b = *(const float4*)&lb[(size_t)i * 4];
    float bw[4] = {b.x, b.y, b.z, b.w};
    int bbi = 0; float bm = bw[0];
#pragma unroll
    for (int c = 1; c < 4; ++c) if (bw[c] > bm) { bm = bw[c]; bbi = c; }
    argB[i] = bbi;
    float p = pa[i];
#pragma unroll
    for (int off = 32; off > 0; off >>= 1) p += __shfl_down(p, off, 64);
    if ((threadIdx.x & 63) == 0) atomicAdd(&acc[ACC_PA], p);
}

// f32 -> bf16 bulk cast; grid 2048x256, 4 float4-groups/thread
__global__ __launch_bounds__(256) void cast_bf_kernel(
    const float* __restrict__ src, unsigned short* __restrict__ dst) {
    int tid = blockIdx.x * 256 + threadIdx.x;      // < 524288
#pragma unroll
    for (int k = 0; k < 4; ++k) {
        int i4 = tid + k * 524288;                 // < 2097152
        float4 v = *(const float4*)&src[(size_t)i4 * 4];
        ushort4 o;
        o.x = f2bf(v.x); o.y = f2bf(v.y); o.z = f2bf(v.z); o.w = f2bf(v.w);
        *(ushort4*)&dst[(size_t)i4 * 4] = o;
    }
}

// W[256][256] f32 -> Wt[n][k] bf16 (transposed)
__global__ __launch_bounds__(256) void cast_wt_kernel(
    const float* __restrict__ W, unsigned short* __restrict__ Wt) {
    __shared__ float tile[16][17];
    int tx = threadIdx.x & 15, ty = threadIdx.x >> 4;
    int bx = blockIdx.x, by = blockIdx.y;
    tile[ty][tx] = W[(size_t)(by * 16 + ty) * 256 + bx * 16 + tx];
    __syncthreads();
    Wt[(size_t)(bx * 16 + ty) * 256 + by * 16 + tx] = f2bf(tile[tx][ty]);
}

// Y(bf16) = X(bf16, Mx256) @ W via Wt (bf16, transposed [n][k])
__global__ __launch_bounds__(256) void gemm_bf_kernel(
    const unsigned short* __restrict__ X, const unsigned short* __restrict__ Wt,
    unsigned short* __restrict__ Y) {
    __shared__ unsigned short Xs[64 * 40];
    __shared__ unsigned short Ws[256 * 40];
    const int t = threadIdx.x;
    const int L = t & 63, wv = t >> 6;
    const int q = L >> 4, n = L & 15;
    const size_t row0 = (size_t)blockIdx.x * 64;
    f32x4 acc[16];
#pragma unroll
    for (int nt = 0; nt < 16; ++nt) acc[nt] = (f32x4){0.f, 0.f, 0.f, 0.f};

    for (int k0 = 0; k0 < 256; k0 += 32) {
        {
            int r = t >> 2, seg = t & 3;
            *(uint4*)&Xs[r * 40 + seg * 8] =
                *(const uint4*)&X[(row0 + r) * 256 + k0 + seg * 8];
#pragma unroll
            for (int it = 0; it < 4; ++it) {
                int nn = (t >> 2) + it * 64;
                *(uint4*)&Ws[nn * 40 + seg * 8] =
                    *(const uint4*)&Wt[(size_t)nn * 256 + k0 + seg * 8];
            }
        }
        __syncthreads();
        bf16x8 av = *(const bf16x8*)&Xs[(wv * 16 + n) * 40 + q * 8];
#pragma unroll
        for (int nt = 0; nt < 16; ++nt) {
            bf16x8 bv = *(const bf16x8*)&Ws[(nt * 16 + n) * 40 + q * 8];
            acc[nt] = __builtin_amdgcn_mfma_f32_16x16x32_bf16(av, bv, acc[nt], 0, 0, 0);
        }
        __syncthreads();
    }
#pragma unroll
    for (int nt = 0; nt < 16; ++nt)
#pragma unroll
        for (int r = 0; r < 4; ++r) {
            size_t row = row0 + wv * 16 + q * 4 + r;
            Y[row * 256 + nt * 16 + n] = f2bf(acc[nt][r]);
        }
}

// y_bf16_out = LN(leaky_relu(y_bf16_in + bias)) * g + be ; optional row sq-norms
__global__ __launch_bounds__(256) void ln_bf_kernel(
    const unsigned short* __restrict__ Yin, unsigned short* __restrict__ Yout,
    const float* __restrict__ bias, const float* __restrict__ gam,
    const float* __restrict__ bet, float* __restrict__ norms) {
    int lane = threadIdx.x & 63;
    int wv = threadIdx.x >> 6;
    size_t row = (size_t)blockIdx.x * 4 + wv;
    ushort4 y4 = *(const ushort4*)&Yin[row * 256 + lane * 4];
    float4 b4 = *(const float4*)&bias[lane * 4];
    float h[4] = {bf2f(y4.x) + b4.x, bf2f(y4.y) + b4.y, bf2f(y4.z) + b4.z, bf2f(y4.w) + b4.w};
#pragma unroll
    for (int e = 0; e < 4; ++e) h[e] = h[e] >= 0.f ? h[e] : 0.01f * h[e];
    float s = h[0] + h[1] + h[2] + h[3];
    float sq = h[0] * h[0] + h[1] * h[1] + h[2] * h[2] + h[3] * h[3];
#pragma unroll
    for (int off = 32; off > 0; off >>= 1) {
        s += __shfl_down(s, off, 64);
        sq += __shfl_down(sq, off, 64);
    }
    s = __shfl(s, 0, 64); sq = __shfl(sq, 0, 64);
    float mean = s * (1.f / 256.f);
    float var = fmaxf(sq * (1.f / 256.f) - mean * mean, 0.f);
    float inv = rsqrtf(var + 1e-5f);
    float4 g4 = *(const float4*)&gam[lane * 4];
    float4 e4 = *(const float4*)&bet[lane * 4];
    float gv[4] = {g4.x, g4.y, g4.z, g4.w};
    float ev[4] = {e4.x, e4.y, e4.z, e4.w};
    ushort4 o4; float nr = 0.f;
    {
        unsigned short ob[4];
#pragma unroll
        for (int e = 0; e < 4; ++e) {
            float o = (h[e] - mean) * inv * gv[e] + ev[e];
            ob[e] = f2bf(o);
            float orr = bf2f(ob[e]);
            nr += orr * orr;
        }
        o4.x = ob[0]; o4.y = ob[1]; o4.z = ob[2]; o4.w = ob[3];
    }
    *(ushort4*)&Yout[row * 256 + lane * 4] = o4;
    if (norms) {
#pragma unroll
        for (int off = 32; off > 0; off >>= 1) nr += __shfl_down(nr, off, 64);
        if (lane == 0) norms[row] = nr;
    }
}

// cdist via MFMA + in/out loss partial + K(bf16) = exp(-2*cost) + K column sums
__global__ __launch_bounds__(256) void cost_mfma_kernel(
    const unsigned short* __restrict__ E, const float* __restrict__ norms,
    const int* __restrict__ argA, const int* __restrict__ argB,
    const float* __restrict__ pa, const float* __restrict__ pb,
    unsigned short* __restrict__ Kb16, float* __restrict__ acc,
    float* __restrict__ colsum) {
    __shared__ unsigned short As[64 * 40];
    __shared__ unsigned short Bs[64 * 40];
    const int t = threadIdx.x;
    const int L = t & 63, wv = t >> 6;
    const int q = L >> 4, n = L & 15;
    const int b = blockIdx.z;
    const int i0 = blockIdx.y * 64, j0 = blockIdx.x * 64;
    const unsigned short* eA = E + (size_t)b * 512 * 256;
    const unsigned short* eB = E + (size_t)(32768 + b * 512) * 256;
    f32x4 dot[4];
#pragma unroll
    for (int nt = 0; nt < 4; ++nt) dot[nt] = (f32x4){0.f, 0.f, 0.f, 0.f};

    for (int k0 = 0; k0 < 256; k0 += 32) {
        int r = t >> 2, seg = t & 3;
        *(uint4*)&As[r * 40 + seg * 8] =
            *(const uint4*)&eA[(size_t)(i0 + r) * 256 + k0 + seg * 8];
        *(uint4*)&Bs[r * 40 + seg * 8] =
            *(const uint4*)&eB[(size_t)(j0 + r) * 256 + k0 + seg * 8];
        __syncthreads();
        bf16x8 av = *(const bf16x8*)&As[(wv * 16 + n) * 40 + q * 8];
#pragma unroll
        for (int nt = 0; nt < 4; ++nt) {
            bf16x8 bv = *(const bf16x8*)&Bs[(nt * 16 + n) * 40 + q * 8];
            dot[nt] = __builtin_amdgcn_mfma_f32_16x16x32_bf16(av, bv, dot[nt], 0, 0, 0);
        }
        __syncthreads();
    }
    int base_row = i0 + wv * 16 + q * 4;
    float nA[4], pA[4]; int cA[4];
#pragma unroll
    for (int r = 0; r < 4; ++r) {
        nA[r] = norms[b * 512 + base_row + r];
        pA[r] = pa[b * 512 + base_row + r];
        cA[r] = argA[b * 512 + base_row + r];
    }
    float part = 0.f;
    float csnt[4];
#pragma unroll
    for (int nt = 0; nt < 4; ++nt) {
        int col = j0 + nt * 16 + n;
        float nB = norms[32768 + b * 512 + col];
        float pB = pb[b * 512 + col];
        int cB = argB[b * 512 + col];
        float cloc = 0.f;
#pragma unroll
        for (int r = 0; r < 4; ++r) {
            float d2 = nA[r] + nB - 2.f * dot[nt][r];
            float c = sqrtf(fmaxf(d2, 0.f));
            float pm = pA[r] * pB;
            float cc = c + (BIGF - BIGF * pm);
            float sgn = (cA[r] == cB) ? 1.f : -1.f;
            part += cc * sgn * pm;
            unsigned short kb = f2bf(expf(-2.f * cc));
            Kb16[((size_t)b * 512 + base_row + r) * 512 + col] = kb;
            cloc += bf2f(kb);
        }
        csnt[nt] = cloc;
    }
    // column sums for sinkhorn's v1 = 1/colsum: reduce over q-groups, waves, row-tiles
    __shared__ float csh[4][64];
#pragma unroll
    for (int nt = 0; nt < 4; ++nt) {
        float sq = csnt[nt];
        sq += __shfl_xor(sq, 16, 64);
        sq += __shfl_xor(sq, 32, 64);
        if (L < 16) csh[wv][nt * 16 + L] = sq;
    }
    __syncthreads();
    if (t < 64)
        atomicAdd(&colsum[(size_t)b * 512 + j0 + t],
                  csh[0][t] + csh[1][t] + csh[2][t] + csh[3][t]);
    float tot = block_reduce_256(part);
    if (threadIdx.x == 0) atomicAdd(&acc[ACC_IN + b], tot);
}

// Fused Sinkhorn, packed reduces. One block per batch, wave owns 32 rows,
// lane l owns cols l*8..+7. v1 = 1/colsum (from cost kernel, staged in u buf).
// 9 fused passes (u(t) row-reduce + col partials for v(t+1)) + 1 final row pass.
// Row reduce: 4 rows jointly in 10 DS ops (vs 24); broadcast via v_readlane (VALU).
__global__ __launch_bounds__(1024) void sinkhorn_kernel(
    const unsigned short* __restrict__ Kb16, float* u, float* __restrict__ v) {
    const int b = blockIdx.x;
    const unsigned short* Kb = Kb16 + (size_t)b * 262144;
    __shared__ float vv[512];
    __shared__ float cp[16][512];
    const int t = threadIdx.x, wv = t >> 6, l = t & 63;
    const unsigned short* base = Kb + (size_t)(wv * 32) * 512 + l * 8;

    // v1_j = (1/512) / (colsum_j/512) = 1/colsum_j  (u buffer holds colsum here)
    if (t < 512) vv[t] = 1.f / u[(size_t)b * 512 + t];
    __syncthreads();

    for (int it = 1; it <= 9; ++it) {
        float vr[8];
        *(f32x4*)&vr[0] = *(const f32x4*)&vv[l * 8];
        *(f32x4*)&vr[4] = *(const f32x4*)&vv[l * 8 + 4];
        float cs[8];
#pragma unroll
        for (int e = 0; e < 8; ++e) cs[e] = 0.f;
#pragma unroll 2
        for (int g = 0; g < 8; ++g) {
            const unsigned short* gb = base + (size_t)(g * 4) * 512;
            uint4 w0 = *(const uint4*)(gb);
            uint4 w1 = *(const uint4*)(gb + 512);
            uint4 w2 = *(const uint4*)(gb + 1024);
            uint4 w3 = *(const uint4*)(gb + 1536);
            float k0[8], k1[8], k2[8], k3[8];
            unpack8(w0, k0); unpack8(w1, k1); unpack8(w2, k2); unpack8(w3, k3);
            float p0 = dot8(k0, vr);
            float p1 = dot8(k1, vr);
            float p2 = dot8(k2, vr);
            float p3 = dot8(k3, vr);
            float s = packed_reduce4(p0, p1, p2, p3, l);
            float us = 0.001953125f * __builtin_amdgcn_rcpf(s);
            float uA = bcast_lane(us, 0);
            float uC = bcast_lane(us, 16);
            float uB = bcast_lane(us, 32);
            float uD = bcast_lane(us, 48);
#pragma unroll
            for (int e = 0; e < 8; ++e) {
                float c = fmaf(k0[e], uA, cs[e]);
                c = fmaf(k1[e], uB, c);
                c = fmaf(k2[e], uC, c);
                cs[e] = fmaf(k3[e], uD, c);
            }
        }
        *(f32x4*)&cp[wv][l * 8]     = *(f32x4*)&cs[0];
        *(f32x4*)&cp[wv][l * 8 + 4] = *(f32x4*)&cs[4];
        __syncthreads();
        if (t < 512) {
            float ss = 0.f;
#pragma unroll
            for (int k = 0; k < 16; ++k) ss += cp[k][t];
            vv[t] = (1.f / 512.f) / ss;
        }
        __syncthreads();
    }

    // final pass: u(10) from v(10), exact divide, direct global write
    {
        float vr[8];
        *(f32x4*)&vr[0] = *(const f32x4*)&vv[l * 8];
        *(f32x4*)&vr[4] = *(const f32x4*)&vv[l * 8 + 4];
#pragma unroll 2
        for (int g = 0; g < 8; ++g) {
            const unsigned short* gb = base + (size_t)(g * 4) * 512;
            uint4 w0 = *(const uint4*)(gb);
            uint4 w1 = *(const uint4*)(gb + 512);
            uint4 w2 = *(const uint4*)(gb + 1024);
            uint4 w3 = *(const uint4*)(gb + 1536);
            float k0[8], k1[8], k2[8], k3[8];
            unpack8(w0, k0); unpack8(w1, k1); unpack8(w2, k2); unpack8(w3, k3);
            float p0 = dot8(k0, vr);
            float p1 = dot8(k1, vr);
            float p2 = dot8(k2, vr);
            float p3 = dot8(k3, vr);
            float s = packed_reduce4(p0, p1, p2, p3, l);
            if ((l & 15) == 0) {
                int g16 = l >> 4;
                int rof = ((g16 & 1) << 1) | (g16 >> 1);   // 0,2,1,3
                u[(size_t)b * 512 + wv * 32 + g * 4 + rof] = 0.001953125f / s;
            }
        }
    }
    if (t < 512) v[(size_t)b * 512 + t] = vv[t];
}

// sup loss on bf16 K
__global__ __launch_bounds__(256) void sup_kernel(
    const unsigned short* __restrict__ Kb16, const float* __restrict__ u,
    const float* __restrict__ v, const float* __restrict__ rel,
    const float* __restrict__ pa, float* __restrict__ acc) {
    const int nthreads = 4096 * 256;
    int tid = blockIdx.x * 256 + threadIdx.x;
    float part = 0.f;
#pragma unroll
    for (int k = 0; k < 4; ++k) {
        int i4 = tid + k * nthreads;
        int e = i4 * 4;
        int b = e >> 18;
        int i = (e >> 9) & 511;
        int j0 = e & 511;
        ushort4 K4 = *(const ushort4*)&Kb16[(size_t)i4 * 4];
        float4 r4 = *(const float4*)&rel[(size_t)i4 * 4];
        float4 v4 = *(const float4*)&v[b * 512 + j0];
        float ui = u[b * 512 + i] * 512.f;
        float pai = pa[b * 512 + i];
        float d0 = ui * bf2f(K4.x) * v4.x - r4.x;
        float d1 = ui * bf2f(K4.y) * v4.y - r4.y;
        float d2 = ui * bf2f(K4.z) * v4.z - r4.z;
        float d3 = ui * bf2f(K4.w) * v4.w - r4.w;
        part += (d0 * d0 + d1 * d1 + d2 * d2 + d3 * d3) * pai;
    }
    float tot = block_reduce_256(part);
    if (threadIdx.x == 0) atomicAdd(&acc[ACC_SUP + (blockIdx.x & 255)], tot);
}

__global__ __launch_bounds__(256) void final_kernel(const float* __restrict__ acc,
                                                    float* __restrict__ out) {
    int t = threadIdx.x;
    float vin = (t < 64) ? acc[ACC_IN + t] : 0.f;
    float sIn = block_reduce_256(vin);
    float vsup = acc[ACC_SUP + t];
    float sSup = block_reduce_256(vsup);
    if (t == 0)
        out[0] = sIn * (1.f / 16777216.f) + 10.f * sSup / acc[ACC_PA];
}

extern "C" void kernel_launch(void* const* d_in, const int* in_sizes, int n_in,
                              void* d_out, int out_size, void* d_ws, size_t ws_size,
                              hipStream_t stream) {
    const float* la  = (const float*)d_in[0];
    const float* lb  = (const float*)d_in[1];
    const float* xA  = (const float*)d_in[2];
    const float* xB  = (const float*)d_in[3];
    const float* rel = (const float*)d_in[4];
    const float* pa  = (const float*)d_in[5];
    const float* pb  = (const float*)d_in[6];
    const float* W1  = (const float*)d_in[7];
    const float* b1  = (const float*)d_in[8];
    const float* g1  = (const float*)d_in[9];
    const float* be1 = (const float*)d_in[10];
    const float* W2  = (const float*)d_in[11];
    const float* b2  = (const float*)d_in[12];
    const float* g2  = (const float*)d_in[13];
    const float* be2 = (const float*)d_in[14];
    float* out = (float*)d_out;

    float* ws = (float*)d_ws;
    unsigned short* Kb16 = (unsigned short*)(ws + KB_OFF);   // Ybf1/Ybf2 then K
    unsigned short* Xbf  = (unsigned short*)(ws + X_OFF);    // Xbf then Ebf
    unsigned short* Hbf  = (unsigned short*)(ws + H_OFF);
    float* norms = ws + NORM_OFF;
    float* u     = ws + U_OFF;    // colsum staging, then u output
    float* v     = ws + V_OFF;
    int* argA    = (int*)(ws + ARGA_OFF);
    int* argB    = (int*)(ws + ARGB_OFF);
    float* acc   = ws + ACC_OFF;
    unsigned short* Wt1 = (unsigned short*)(ws + WT1_OFF);
    unsigned short* Wt2 = (unsigned short*)(ws + WT2_OFF);

    zero_acc_kernel<<<128, 256, 0, stream>>>(acc, u);        // zero acc + colsum
    argmax_pa_kernel<<<128, 256, 0, stream>>>(la, lb, pa, argA, argB, acc);

    // casts
    cast_bf_kernel<<<2048, 256, 0, stream>>>(xA, Xbf);
    cast_bf_kernel<<<2048, 256, 0, stream>>>(xB, Xbf + (size_t)MROWS * DIM);
    cast_wt_kernel<<<dim3(16, 16), 256, 0, stream>>>(W1, Wt1);
    cast_wt_kernel<<<dim3(16, 16), 256, 0, stream>>>(W2, Wt2);

    // layer 1
    gemm_bf_kernel<<<1024, 256, 0, stream>>>(Xbf, Wt1, Kb16);
    ln_bf_kernel<<<16384, 256, 0, stream>>>(Kb16, Hbf, b1, g1, be1, nullptr);
    // layer 2
    gemm_bf_kernel<<<1024, 256, 0, stream>>>(Hbf, Wt2, Kb16);
    ln_bf_kernel<<<16384, 256, 0, stream>>>(Kb16, Xbf, b2, g2, be2, norms);  // Ebf -> Xbf buf

    // cost + K (bf16) + column sums
    cost_mfma_kernel<<<dim3(8, 8, 64), 256, 0, stream>>>(Xbf, norms, argA, argB, pa, pb,
                                                         Kb16, acc, u);

    // sinkhorn: 10 K-passes (pass-0 folded into cost via colsum)
    sinkhorn_kernel<<<64, 1024, 0, stream>>>(Kb16, u, v);

    sup_kernel<<<4096, 256, 0, stream>>>(Kb16, u, v, rel, pa, acc);
    final_kernel<<<1, 256, 0, stream>>>(acc, out);
}